// Round 2
// baseline (228.004 us; speedup 1.0000x reference)
//
#include <hip/hip_runtime.h>
#include <math.h>

// B=32 graphs, N=1024 nodes, D=128 in-dim, C=64 out-dim, K=16.
#define OUT_ELEMS 2097152   // 32768*64
#define EDGE_ELEMS 524288   // 32*1024*16
#define NROWS 32768
#define CAND_STRIDE 128

__device__ __forceinline__ unsigned int rotl32(unsigned int x, int r){
  return (x << r) | (x >> (32 - r));
}

// JAX partitionable threefry, key (0,1): counter = (0, e); out = o0 ^ o1.
__device__ __forceinline__ unsigned int tf_bits_part(unsigned int e){
  unsigned int x0 = 0u, x1 = e;
  const unsigned int ks1 = 1u;
  const unsigned int ks2 = 0x1BD11BDBu;
  x1 += ks1;
#define TFR(r) { x0 += x1; x1 = rotl32(x1, r); x1 ^= x0; }
  TFR(13) TFR(15) TFR(26) TFR(6)
  x0 += ks1; x1 += ks2 + 1u;
  TFR(17) TFR(29) TFR(16) TFR(24)
  x0 += ks2; x1 += 0u + 2u;
  TFR(13) TFR(15) TFR(26) TFR(6)
  x0 += 0u;  x1 += ks1 + 3u;
  TFR(17) TFR(29) TFR(16) TFR(24)
  x0 += ks1; x1 += ks2 + 4u;
  TFR(13) TFR(15) TFR(26) TFR(6)
  x0 += ks2; x1 += 0u + 5u;
#undef TFR
  return x0 ^ x1;
}

// hardware f64 reciprocal + 2 Newton steps: rel err ~1e-16.
__device__ __forceinline__ double rcp64(double x){
  double r;
  asm("v_rcp_f64 %0, %1" : "=v"(r) : "v"(x));
  double e = fma(-x, r, 1.0); r = fma(r, e, r);
  e = fma(-x, r, 1.0); r = fma(r, e, r);
  return r;
}

// fast e^x for x in [-740, ~1]; rel err ~2e-11 (deg-9).
__device__ __forceinline__ double fast_exp(double x){
  double fn = __builtin_rint(x * 1.4426950408889634);
  int n = (int)fn;
  double r = fma(fn, -0.6931471803691238, x);
  r = fma(fn, -1.9082149292705877e-10, r);
  double p = 2.7557319223985893e-06;
  p = fma(r, p, 2.4801587301587302e-05);
  p = fma(r, p, 1.9841269841269841e-04);
  p = fma(r, p, 1.3888888888888889e-03);
  p = fma(r, p, 8.3333333333333333e-03);
  p = fma(r, p, 4.1666666666666664e-02);
  p = fma(r, p, 1.6666666666666666e-01);
  p = fma(r, p, 0.5);
  p = fma(r, p, 1.0);
  p = fma(r, p, 1.0);
  double scale = __longlong_as_double(((long long)(n + 1023)) << 52);
  return p * scale;
}

// fast ln(x), normal positive x; atanh form; abs err ~2e-11.
__device__ __forceinline__ double fast_log(double x){
  long long bx = __double_as_longlong(x);
  long long e = (bx >> 52) - 1023;
  double m = __longlong_as_double((bx & 0xFFFFFFFFFFFFFll) |
                                  0x3FF0000000000000ll);
  int big = m > 1.4142135623730951;
  m = big ? 0.5 * m : m;
  e += big;
  double s = (m - 1.0) * rcp64(m + 1.0);
  double s2 = s * s;
  double p = fma(s2, 2.0/11.0, 2.0/9.0);
  p = fma(s2, p, 2.0/7.0);
  p = fma(s2, p, 2.0/5.0);
  p = fma(s2, p, 2.0/3.0);
  double lm = fma(s * s2, p, 2.0 * s);
  return fma((double)e, 0.6931471805599453, lm);
}

// Exact f64 score of candidate jc. Accumulation order q=0..63 sequential —
// bit-identical to v5..v11. unroll 4: only 4 float4 loads in flight.
__device__ __forceinline__ unsigned long long score_cand(
    const float* __restrict__ og, const double* __restrict__ hrow,
    unsigned int jc, unsigned int base, double Td, bool act){
  const float4* cp4 = (const float4*)(og + ((size_t)jc << 6));
  double acc = 0.0;
  #pragma unroll 4
  for (int ch = 0; ch < 16; ++ch){
    float4 cf = cp4[ch];
    double d0 = hrow[(ch << 2) + 0] - (double)cf.x;
    double d1 = hrow[(ch << 2) + 1] - (double)cf.y;
    double d2 = hrow[(ch << 2) + 2] - (double)cf.z;
    double d3 = hrow[(ch << 2) + 3] - (double)cf.w;
    acc = fma(d0, d0, acc);
    acc = fma(d1, d1, acc);
    acc = fma(d2, d2, acc);
    acc = fma(d3, d3, acc);
  }
  if (!act) return 0ull;
  double sgm = fast_exp(-Td * acc);
  unsigned int bits = tf_bits_part(base | jc);
  float f = __uint_as_float(0x3f800000u | (bits >> 9)) - 1.0f;
  double u = (f > 0.0f) ? (double)f : 1.1754943508222875e-38;
  double w = -fast_log(u);
  double z = -fast_log(w);
  double sc = sgm + z;
  unsigned long long kb = (unsigned long long)__double_as_longlong(sc);
  kb ^= (unsigned long long)(((long long)kb) >> 63) | 0x8000000000000000ull;
  return (kb & ~1023ull) | (unsigned long long)(1023u - jc);
}

// Full descending bitonic sort of u64 keys across 64 lanes.
__device__ __forceinline__ unsigned long long bitonic64_desc(
    unsigned long long key, int lane){
  #pragma unroll
  for (int k = 2; k <= 64; k <<= 1){
    #pragma unroll
    for (int j = k >> 1; j; j >>= 1){
      unsigned long long o = __shfl_xor(key, j, 64);
      bool keep_hi = ((lane & k) == 0) == ((lane & j) == 0);
      key = (keep_hi == (o > key)) ? o : key;
    }
  }
  return key;
}

// Full descending bitonic sort of u32 keys across 64 lanes.
__device__ __forceinline__ unsigned int bitonic32_desc(
    unsigned int key, int lane){
  #pragma unroll
  for (int k = 2; k <= 64; k <<= 1){
    #pragma unroll
    for (int j = k >> 1; j; j >>= 1){
      unsigned int o = __shfl_xor(key, j, 64);
      bool keep_hi = ((lane & k) == 0) == ((lane & j) == 0);
      key = (keep_hi == (o > key)) ? o : key;
    }
  }
  return key;
}

// ---------------- K1: fused encoder + candidate generation ----------------
// Edges phases 1-3 (threefry noise, cheap cut, compaction) depend only on
// indices, NOT on `out`. So they run CONCURRENTLY with the encoder as
// heterogeneous blocks of one kernel: blockIdx%9==0 -> encoder block (f64
// pipe + memory), else candidate-gen block (pure int VALU, zero memory
// traffic). 1:8 interleave keeps every CU's pipes mixed. No sync needed.
// Candidate lists (same j values, same slot order as v11's LDS cl[]) go to
// workspace as u16; scoring kernel reads them -> bit-identical output.
__global__ __launch_bounds__(256, 4) void fused_enc_cand_v12(
    const float* __restrict__ x, const float* __restrict__ W,
    const float* __restrict__ b, float* __restrict__ out,
    unsigned short* __restrict__ cand, unsigned int* __restrict__ cntg){
  const unsigned int bid = blockIdx.x;
  const unsigned int q = bid / 9u;        // magic-mul, cheap
  const unsigned int t = bid - q * 9u;
  const int tid = threadIdx.x;
  const int lane = tid & 63;

  if (t == 0u){
    // ---- encoder block eb = q (v11 structure, bit-identical out) ----
    const int wu = __builtin_amdgcn_readfirstlane(tid >> 6);
    const size_t r0 = ((size_t)q << 5) + ((size_t)wu << 3);
    const float* __restrict__ xr = x + (r0 << 7);   // 8 rows x 128, uniform

    double acc[8];
    const double bc = (double)b[lane];
    #pragma unroll
    for (int i = 0; i < 8; ++i) acc[i] = bc;

    #pragma unroll 4
    for (int k = 0; k < 128; ++k){
      const double wk = (double)W[(k << 6) + lane];
      #pragma unroll
      for (int i = 0; i < 8; ++i)
        acc[i] = fma((double)xr[((size_t)i << 7) + k], wk, acc[i]);
    }

    #pragma unroll
    for (int i = 0; i < 8; ++i)
      out[((r0 + i) << 6) + lane] = (float)acc[i];
  } else {
    // ---- candidate-gen block cb = 8q + t-1, rows 4cb..4cb+3 ----
    const unsigned int cb = (q << 3) + t - 1u;
    const int wave = tid >> 6;
    const int gb = (int)(cb >> 8);
    const int i0 = (int)(cb & 255u) << 2;
    const int r  = i0 + wave;
    const unsigned int base = ((unsigned int)gb << 20) | ((unsigned int)r << 10);

    // Phase 1: bits for j = m*64 + lane, with running per-lane max
    unsigned int v[16];
    unsigned int pmax = 0u;
    #pragma unroll
    for (int m = 0; m < 16; ++m){
      const unsigned int j = (unsigned int)(m << 6) + (unsigned int)lane;
      unsigned int bits = tf_bits_part(base | j);
      v[m] = (bits & ~1023u) | (1023u - j);   // low 10 bits don't feed u
      pmax = (v[m] > pmax) ? v[m] : pmax;
    }

    // Phase 2: 16th-largest lane-max (conservative surrogate for b16)
    unsigned int sorted = bitonic32_desc(pmax, lane);
    unsigned int b16p = __shfl(sorted, 15, 64);

    // conservative cut: keep j iff z_j >= z(b16') - 1.001  (score <= z + 1)
    float u16v = __uint_as_float(0x3f800000u | (b16p >> 9)) - 1.0f;
    float z16 = -__logf(-__logf(u16v));
    float uc  = __expf(-__expf(-(z16 - 1.001f)));
    unsigned int cp = ((__float_as_uint(1.0f + uc) & 0x7FFFFFu) << 9) & ~1023u;

    // Phase 3: compaction of all survivors (>=16 guaranteed since cut < b16')
    int cnt = 0;
    #pragma unroll
    for (int m = 0; m < 16; ++m) cnt += (v[m] >= cp) ? 1 : 0;
    int s = cnt;
    #pragma unroll
    for (int off = 1; off < 64; off <<= 1){
      int o = __shfl_up(s, off, 64);
      s += (lane >= off) ? o : 0;
    }
    int nc = __shfl(s, 63, 64);
    nc = (nc > 128) ? 128 : nc;
    int slot = s - cnt;
    unsigned short* __restrict__ crow =
        cand + (size_t)(((unsigned int)gb << 10) + (unsigned int)r) * CAND_STRIDE;
    #pragma unroll
    for (int m = 0; m < 16; ++m){
      if (v[m] >= cp && slot < 128){
        crow[slot] = (unsigned short)(1023u - (v[m] & 1023u));
        ++slot;
      }
    }
    if (lane == 0) cntg[((unsigned int)gb << 10) + (unsigned int)r] = (unsigned int)nc;
  }
}

// ---------------- K2: exact scoring + top-16 (edges phase 4) ----------------
// Identical math to v11 phase 4; candidates come from workspace (same values,
// same order as the LDS cl[] they replace) -> bit-identical keys -> identical
// sort result -> identical edge output.
__global__ __launch_bounds__(256, 8) void edges_score_v12(
    const float* __restrict__ out32, const float* __restrict__ temp,
    const unsigned short* __restrict__ cand,
    const unsigned int* __restrict__ cntg,
    float* __restrict__ rows_out, float* __restrict__ cols_out){
  __shared__ double hid[4][64];         // 2 KB
  const int tid = threadIdx.x, wave = tid >> 6, lane = tid & 63;
  const int gb = blockIdx.x >> 8;
  const int i0 = (blockIdx.x & 255) << 2;
  const int r  = i0 + wave;
  const float* __restrict__ og = out32 + ((size_t)gb << 16);

  hid[wave][lane] = (double)og[((size_t)r << 6) + lane];

  const unsigned int base = ((unsigned int)gb << 20) | ((unsigned int)r << 10);
  const int grow = (gb << 10) + r;
  const int nc = (int)cntg[grow];
  const unsigned short* __restrict__ cl = cand + (size_t)grow * CAND_STRIDE;

  const double Td = (double)temp[0];
  const bool act1 = (lane < nc);
  unsigned int jc1 = act1 ? (unsigned int)cl[lane] : 0u;
  unsigned long long key = score_cand(og, hid[wave], jc1, base, Td, act1);
  key = bitonic64_desc(key, lane);

  if (nc > 64){
    const int idx2 = 64 + lane;
    const bool act2 = (idx2 < nc);
    unsigned int jc2 = act2 ? (unsigned int)cl[idx2] : 0u;
    unsigned long long k2 = score_cand(og, hid[wave], jc2, base, Td, act2);
    k2 = bitonic64_desc(k2, lane);
    unsigned long long kr = __shfl(k2, 63 - lane, 64);
    key = (kr > key) ? kr : key;          // elementwise top-64 (bitonic)
    #pragma unroll
    for (int j = 32; j; j >>= 1){         // descending clean
      unsigned long long o = __shfl_xor(key, j, 64);
      bool left = (lane & j) == 0;
      bool take = left ? (o > key) : (o < key);
      key = take ? o : key;
    }
  }

  if (lane < 16){
    rows_out[((size_t)grow << 4) + lane] = (float)grow;
    cols_out[((size_t)grow << 4) + lane] =
        (float)((gb << 10) + (1023 - (int)(key & 1023ull)));
  }
}

extern "C" void kernel_launch(void* const* d_in, const int* in_sizes, int n_in,
                              void* d_out, int out_size, void* d_ws, size_t ws_size,
                              hipStream_t stream){
  const float* x = (const float*)d_in[0];
  const float* W = (const float*)d_in[1];
  const float* b = (const float*)d_in[2];
  const float* T = (const float*)d_in[3];
  float* out      = (float*)d_out;
  float* rows_out = out + OUT_ELEMS;
  float* cols_out = rows_out + EDGE_ELEMS;

  // workspace: u16 candidate lists (8 MB) + u32 counts (128 KB)
  unsigned short* cand = (unsigned short*)d_ws;
  unsigned int*   cntg = (unsigned int*)((char*)d_ws +
                          (size_t)NROWS * CAND_STRIDE * sizeof(unsigned short));

  fused_enc_cand_v12<<<9216, 256, 0, stream>>>(x, W, b, out, cand, cntg);
  edges_score_v12<<<8192, 256, 0, stream>>>(out, T, cand, cntg,
                                            rows_out, cols_out);
}

// Round 3
// 213.915 us; speedup vs baseline: 1.0659x; 1.0659x over previous
//
#include <hip/hip_runtime.h>
#include <math.h>

// B=32 graphs, N=1024 nodes, D=128 in-dim, C=64 out-dim, K=16.
#define OUT_ELEMS 2097152   // 32768*64
#define EDGE_ELEMS 524288   // 32*1024*16

__device__ __forceinline__ unsigned int rotl32(unsigned int x, int r){
  return (x << r) | (x >> (32 - r));
}

// JAX partitionable threefry, key (0,1): counter = (0, e); out = o0 ^ o1.
__device__ __forceinline__ unsigned int tf_bits_part(unsigned int e){
  unsigned int x0 = 0u, x1 = e;
  const unsigned int ks1 = 1u;
  const unsigned int ks2 = 0x1BD11BDBu;
  x1 += ks1;
#define TFR(r) { x0 += x1; x1 = rotl32(x1, r); x1 ^= x0; }
  TFR(13) TFR(15) TFR(26) TFR(6)
  x0 += ks1; x1 += ks2 + 1u;
  TFR(17) TFR(29) TFR(16) TFR(24)
  x0 += ks2; x1 += 0u + 2u;
  TFR(13) TFR(15) TFR(26) TFR(6)
  x0 += 0u;  x1 += ks1 + 3u;
  TFR(17) TFR(29) TFR(16) TFR(24)
  x0 += ks1; x1 += ks2 + 4u;
  TFR(13) TFR(15) TFR(26) TFR(6)
  x0 += ks2; x1 += 0u + 5u;
#undef TFR
  return x0 ^ x1;
}

// hardware f64 reciprocal + 2 Newton steps: rel err ~1e-16.
__device__ __forceinline__ double rcp64(double x){
  double r;
  asm("v_rcp_f64 %0, %1" : "=v"(r) : "v"(x));
  double e = fma(-x, r, 1.0); r = fma(r, e, r);
  e = fma(-x, r, 1.0); r = fma(r, e, r);
  return r;
}

// fast e^x for x in [-740, ~1]; rel err ~2e-11 (deg-9).
__device__ __forceinline__ double fast_exp(double x){
  double fn = __builtin_rint(x * 1.4426950408889634);
  int n = (int)fn;
  double r = fma(fn, -0.6931471803691238, x);
  r = fma(fn, -1.9082149292705877e-10, r);
  double p = 2.7557319223985893e-06;
  p = fma(r, p, 2.4801587301587302e-05);
  p = fma(r, p, 1.9841269841269841e-04);
  p = fma(r, p, 1.3888888888888889e-03);
  p = fma(r, p, 8.3333333333333333e-03);
  p = fma(r, p, 4.1666666666666664e-02);
  p = fma(r, p, 1.6666666666666666e-01);
  p = fma(r, p, 0.5);
  p = fma(r, p, 1.0);
  p = fma(r, p, 1.0);
  double scale = __longlong_as_double(((long long)(n + 1023)) << 52);
  return p * scale;
}

// fast ln(x), normal positive x; atanh form; abs err ~2e-11.
__device__ __forceinline__ double fast_log(double x){
  long long bx = __double_as_longlong(x);
  long long e = (bx >> 52) - 1023;
  double m = __longlong_as_double((bx & 0xFFFFFFFFFFFFFll) |
                                  0x3FF0000000000000ll);
  int big = m > 1.4142135623730951;
  m = big ? 0.5 * m : m;
  e += big;
  double s = (m - 1.0) * rcp64(m + 1.0);
  double s2 = s * s;
  double p = fma(s2, 2.0/11.0, 2.0/9.0);
  p = fma(s2, p, 2.0/7.0);
  p = fma(s2, p, 2.0/5.0);
  p = fma(s2, p, 2.0/3.0);
  double lm = fma(s * s2, p, 2.0 * s);
  return fma((double)e, 0.6931471805599453, lm);
}

// Exact f64 score of candidate jc. Accumulation order q=0..63 sequential —
// bit-identical to v5..v11. unroll 4: only 4 float4 loads in flight.
__device__ __forceinline__ unsigned long long score_cand(
    const float* __restrict__ og, const double* __restrict__ hrow,
    unsigned int jc, unsigned int base, double Td, bool act){
  const float4* cp4 = (const float4*)(og + ((size_t)jc << 6));
  double acc = 0.0;
  #pragma unroll 4
  for (int ch = 0; ch < 16; ++ch){
    float4 cf = cp4[ch];
    double d0 = hrow[(ch << 2) + 0] - (double)cf.x;
    double d1 = hrow[(ch << 2) + 1] - (double)cf.y;
    double d2 = hrow[(ch << 2) + 2] - (double)cf.z;
    double d3 = hrow[(ch << 2) + 3] - (double)cf.w;
    acc = fma(d0, d0, acc);
    acc = fma(d1, d1, acc);
    acc = fma(d2, d2, acc);
    acc = fma(d3, d3, acc);
  }
  if (!act) return 0ull;
  double sgm = fast_exp(-Td * acc);
  unsigned int bits = tf_bits_part(base | jc);
  float f = __uint_as_float(0x3f800000u | (bits >> 9)) - 1.0f;
  double u = (f > 0.0f) ? (double)f : 1.1754943508222875e-38;
  double w = -fast_log(u);
  double z = -fast_log(w);
  double sc = sgm + z;
  unsigned long long kb = (unsigned long long)__double_as_longlong(sc);
  kb ^= (unsigned long long)(((long long)kb) >> 63) | 0x8000000000000000ull;
  return (kb & ~1023ull) | (unsigned long long)(1023u - jc);
}

// Full descending bitonic sort of u64 keys across 64 lanes.
__device__ __forceinline__ unsigned long long bitonic64_desc(
    unsigned long long key, int lane){
  #pragma unroll
  for (int k = 2; k <= 64; k <<= 1){
    #pragma unroll
    for (int j = k >> 1; j; j >>= 1){
      unsigned long long o = __shfl_xor(key, j, 64);
      bool keep_hi = ((lane & k) == 0) == ((lane & j) == 0);
      key = (keep_hi == (o > key)) ? o : key;
    }
  }
  return key;
}

// Full descending bitonic sort of u32 keys across 64 lanes.
__device__ __forceinline__ unsigned int bitonic32_desc(
    unsigned int key, int lane){
  #pragma unroll
  for (int k = 2; k <= 64; k <<= 1){
    #pragma unroll
    for (int j = k >> 1; j; j >>= 1){
      unsigned int o = __shfl_xor(key, j, 64);
      bool keep_hi = ((lane & k) == 0) == ((lane & j) == 0);
      key = (keep_hi == (o > key)) ? o : key;
    }
  }
  return key;
}

// ---------------- encoder ----------------
// v13: occupancy fix. v10/v11 ran 4 waves/SIMD with long dependency chains
// (8 rows/wave) -> ~68 us despite ~15 us of issue work. Halve per-wave work:
// 4 rows/wave, 2048 blocks = 8 blocks/CU = 8 waves/SIMD
// (__launch_bounds__(256,8) caps VGPR at 64). float4 x loads, 4-k inner
// groups. Per (row,c) the fma chain is k=0..127 ascending with exact
// f32->f64 cvts -> operand-identical to v10/v11 -> out bit-identical.
__global__ __launch_bounds__(256, 8) void encoder_v13(
    const float* __restrict__ x, const float* __restrict__ W,
    const float* __restrict__ b, float* __restrict__ out){
  const int tid = threadIdx.x;
  const int c  = tid & 63;
  const int wv = tid >> 6;
  const size_t r0 = ((size_t)blockIdx.x << 4) + ((size_t)wv << 2); // 4 rows
  const float* __restrict__ xr = x + (r0 << 7);

  const double bc = (double)b[c];
  double acc0 = bc, acc1 = bc, acc2 = bc, acc3 = bc;

  #pragma unroll 8
  for (int k = 0; k < 128; k += 4){
    const double w0 = (double)W[((k + 0) << 6) + c];
    const double w1 = (double)W[((k + 1) << 6) + c];
    const double w2 = (double)W[((k + 2) << 6) + c];
    const double w3 = (double)W[((k + 3) << 6) + c];
    const float4 xa = *(const float4*)(xr + 0*128 + k);
    const float4 xb = *(const float4*)(xr + 1*128 + k);
    const float4 xc = *(const float4*)(xr + 2*128 + k);
    const float4 xd = *(const float4*)(xr + 3*128 + k);
    acc0 = fma((double)xa.x, w0, acc0);
    acc0 = fma((double)xa.y, w1, acc0);
    acc0 = fma((double)xa.z, w2, acc0);
    acc0 = fma((double)xa.w, w3, acc0);
    acc1 = fma((double)xb.x, w0, acc1);
    acc1 = fma((double)xb.y, w1, acc1);
    acc1 = fma((double)xb.z, w2, acc1);
    acc1 = fma((double)xb.w, w3, acc1);
    acc2 = fma((double)xc.x, w0, acc2);
    acc2 = fma((double)xc.y, w1, acc2);
    acc2 = fma((double)xc.z, w2, acc2);
    acc2 = fma((double)xc.w, w3, acc2);
    acc3 = fma((double)xd.x, w0, acc3);
    acc3 = fma((double)xd.y, w1, acc3);
    acc3 = fma((double)xd.z, w2, acc3);
    acc3 = fma((double)xd.w, w3, acc3);
  }

  out[((r0 + 0) << 6) + c] = (float)acc0;
  out[((r0 + 1) << 6) + c] = (float)acc1;
  out[((r0 + 2) << 6) + c] = (float)acc2;
  out[((r0 + 3) << 6) + c] = (float)acc3;
}

// ---------------- edges ----------------
// Exact v11 edges (proven: ~118.5 us, VGPR 28, VALUBusy 86%).
__global__ __launch_bounds__(256, 8) void edges_v13(
    const float* __restrict__ out32, const float* __restrict__ temp,
    float* __restrict__ rows_out, float* __restrict__ cols_out){
  __shared__ double hid[4][64];         // 2 KB
  __shared__ unsigned int cl[4][128];   // 2 KB
  const int tid = threadIdx.x, wave = tid >> 6, lane = tid & 63;
  const int gb = blockIdx.x >> 8;
  const int i0 = (blockIdx.x & 255) << 2;
  const int r  = i0 + wave;
  const float* __restrict__ og = out32 + ((size_t)gb << 16);

  hid[wave][lane] = (double)og[((size_t)r << 6) + lane];

  const unsigned int base = ((unsigned int)gb << 20) | ((unsigned int)r << 10);

  // Phase 1: bits for j = m*64 + lane, with running per-lane max
  unsigned int v[16];
  unsigned int pmax = 0u;
  #pragma unroll
  for (int m = 0; m < 16; ++m){
    const unsigned int j = (unsigned int)(m << 6) + (unsigned int)lane;
    unsigned int bits = tf_bits_part(base | j);
    v[m] = (bits & ~1023u) | (1023u - j);   // low 10 bits don't feed u
    pmax = (v[m] > pmax) ? v[m] : pmax;
  }

  // Phase 2: 16th-largest lane-max (conservative surrogate for b16)
  unsigned int sorted = bitonic32_desc(pmax, lane);
  unsigned int b16p = __shfl(sorted, 15, 64);

  // conservative cut: keep j iff z_j >= z(b16') - 1.001  (score <= z + 1)
  float u16 = __uint_as_float(0x3f800000u | (b16p >> 9)) - 1.0f;
  float z16 = -__logf(-__logf(u16));
  float uc  = __expf(-__expf(-(z16 - 1.001f)));
  unsigned int cp = ((__float_as_uint(1.0f + uc) & 0x7FFFFFu) << 9) & ~1023u;

  // Phase 3: compaction of all survivors (>=16 guaranteed since cut < b16')
  int cnt = 0;
  #pragma unroll
  for (int m = 0; m < 16; ++m) cnt += (v[m] >= cp) ? 1 : 0;
  int s = cnt;
  #pragma unroll
  for (int off = 1; off < 64; off <<= 1){
    int o = __shfl_up(s, off, 64);
    s += (lane >= off) ? o : 0;
  }
  int nc = __shfl(s, 63, 64);
  nc = (nc > 128) ? 128 : nc;
  int slot = s - cnt;
  #pragma unroll
  for (int m = 0; m < 16; ++m){
    if (v[m] >= cp && slot < 128){
      cl[wave][slot] = 1023u - (v[m] & 1023u);
      ++slot;
    }
  }

  // Phase 4: exact scoring + sort
  const double Td = (double)temp[0];
  const bool act1 = (lane < nc);
  unsigned int jc1 = act1 ? cl[wave][lane] : 0u;
  unsigned long long key = score_cand(og, hid[wave], jc1, base, Td, act1);
  key = bitonic64_desc(key, lane);

  if (nc > 64){
    const int idx2 = 64 + lane;
    const bool act2 = (idx2 < nc);
    unsigned int jc2 = act2 ? cl[wave][idx2] : 0u;
    unsigned long long k2 = score_cand(og, hid[wave], jc2, base, Td, act2);
    k2 = bitonic64_desc(k2, lane);
    unsigned long long kr = __shfl(k2, 63 - lane, 64);
    key = (kr > key) ? kr : key;          // elementwise top-64 (bitonic)
    #pragma unroll
    for (int j = 32; j; j >>= 1){         // descending clean
      unsigned long long o = __shfl_xor(key, j, 64);
      bool left = (lane & j) == 0;
      bool take = left ? (o > key) : (o < key);
      key = take ? o : key;
    }
  }

  const int grow = (gb << 10) + r;
  if (lane < 16){
    rows_out[((size_t)grow << 4) + lane] = (float)grow;
    cols_out[((size_t)grow << 4) + lane] =
        (float)((gb << 10) + (1023 - (int)(key & 1023ull)));
  }
}

extern "C" void kernel_launch(void* const* d_in, const int* in_sizes, int n_in,
                              void* d_out, int out_size, void* d_ws, size_t ws_size,
                              hipStream_t stream){
  const float* x = (const float*)d_in[0];
  const float* W = (const float*)d_in[1];
  const float* b = (const float*)d_in[2];
  const float* T = (const float*)d_in[3];
  float* out      = (float*)d_out;
  float* rows_out = out + OUT_ELEMS;
  float* cols_out = rows_out + EDGE_ELEMS;

  encoder_v13<<<2048, 256, 0, stream>>>(x, W, b, out);
  edges_v13<<<8192, 256, 0, stream>>>(out, T, rows_out, cols_out);
}

// Round 5
// 189.189 us; speedup vs baseline: 1.2052x; 1.1307x over previous
//
#include <hip/hip_runtime.h>
#include <math.h>

// B=32 graphs, N=1024 nodes, D=128 in-dim, C=64 out-dim, K=16.
#define OUT_ELEMS 2097152   // 32768*64
#define EDGE_ELEMS 524288   // 32*1024*16

__device__ __forceinline__ unsigned int rotl32(unsigned int x, int r){
  return (x << r) | (x >> (32 - r));
}

// JAX partitionable threefry, key (0,1): counter = (0, e); out = o0 ^ o1.
__device__ __forceinline__ unsigned int tf_bits_part(unsigned int e){
  unsigned int x0 = 0u, x1 = e;
  const unsigned int ks1 = 1u;
  const unsigned int ks2 = 0x1BD11BDBu;
  x1 += ks1;
#define TFR(r) { x0 += x1; x1 = rotl32(x1, r); x1 ^= x0; }
  TFR(13) TFR(15) TFR(26) TFR(6)
  x0 += ks1; x1 += ks2 + 1u;
  TFR(17) TFR(29) TFR(16) TFR(24)
  x0 += ks2; x1 += 0u + 2u;
  TFR(13) TFR(15) TFR(26) TFR(6)
  x0 += 0u;  x1 += ks1 + 3u;
  TFR(17) TFR(29) TFR(16) TFR(24)
  x0 += ks1; x1 += ks2 + 4u;
  TFR(13) TFR(15) TFR(26) TFR(6)
  x0 += ks2; x1 += 0u + 5u;
#undef TFR
  return x0 ^ x1;
}

// hardware f64 reciprocal + 2 Newton steps: rel err ~1e-16.
__device__ __forceinline__ double rcp64(double x){
  double r;
  asm("v_rcp_f64 %0, %1" : "=v"(r) : "v"(x));
  double e = fma(-x, r, 1.0); r = fma(r, e, r);
  e = fma(-x, r, 1.0); r = fma(r, e, r);
  return r;
}

// fast e^x for x in [-740, ~1]; rel err ~2e-11 (deg-9).
__device__ __forceinline__ double fast_exp(double x){
  double fn = __builtin_rint(x * 1.4426950408889634);
  int n = (int)fn;
  double r = fma(fn, -0.6931471803691238, x);
  r = fma(fn, -1.9082149292705877e-10, r);
  double p = 2.7557319223985893e-06;
  p = fma(r, p, 2.4801587301587302e-05);
  p = fma(r, p, 1.9841269841269841e-04);
  p = fma(r, p, 1.3888888888888889e-03);
  p = fma(r, p, 8.3333333333333333e-03);
  p = fma(r, p, 4.1666666666666664e-02);
  p = fma(r, p, 1.6666666666666666e-01);
  p = fma(r, p, 0.5);
  p = fma(r, p, 1.0);
  p = fma(r, p, 1.0);
  double scale = __longlong_as_double(((long long)(n + 1023)) << 52);
  return p * scale;
}

// fast ln(x), normal positive x; atanh form; abs err ~2e-11.
__device__ __forceinline__ double fast_log(double x){
  long long bx = __double_as_longlong(x);
  long long e = (bx >> 52) - 1023;
  double m = __longlong_as_double((bx & 0xFFFFFFFFFFFFFll) |
                                  0x3FF0000000000000ll);
  int big = m > 1.4142135623730951;
  m = big ? 0.5 * m : m;
  e += big;
  double s = (m - 1.0) * rcp64(m + 1.0);
  double s2 = s * s;
  double p = fma(s2, 2.0/11.0, 2.0/9.0);
  p = fma(s2, p, 2.0/7.0);
  p = fma(s2, p, 2.0/5.0);
  p = fma(s2, p, 2.0/3.0);
  double lm = fma(s * s2, p, 2.0 * s);
  return fma((double)e, 0.6931471805599453, lm);
}

// Exact f64 score of candidate jc. Accumulation order q=0..63 sequential —
// bit-identical to v5..v13. unroll 4: only 4 float4 loads in flight.
__device__ __forceinline__ unsigned long long score_cand(
    const float* __restrict__ og, const double* __restrict__ hrow,
    unsigned int jc, unsigned int base, double Td, bool act){
  const float4* cp4 = (const float4*)(og + ((size_t)jc << 6));
  double acc = 0.0;
  #pragma unroll 4
  for (int ch = 0; ch < 16; ++ch){
    float4 cf = cp4[ch];
    double d0 = hrow[(ch << 2) + 0] - (double)cf.x;
    double d1 = hrow[(ch << 2) + 1] - (double)cf.y;
    double d2 = hrow[(ch << 2) + 2] - (double)cf.z;
    double d3 = hrow[(ch << 2) + 3] - (double)cf.w;
    acc = fma(d0, d0, acc);
    acc = fma(d1, d1, acc);
    acc = fma(d2, d2, acc);
    acc = fma(d3, d3, acc);
  }
  if (!act) return 0ull;
  double sgm = fast_exp(-Td * acc);
  unsigned int bits = tf_bits_part(base | jc);
  float f = __uint_as_float(0x3f800000u | (bits >> 9)) - 1.0f;
  double u = (f > 0.0f) ? (double)f : 1.1754943508222875e-38;
  double w = -fast_log(u);
  double z = -fast_log(w);
  double sc = sgm + z;
  unsigned long long kb = (unsigned long long)__double_as_longlong(sc);
  kb ^= (unsigned long long)(((long long)kb) >> 63) | 0x8000000000000000ull;
  return (kb & ~1023ull) | (unsigned long long)(1023u - jc);
}

// Full descending bitonic sort of u64 keys across 64 lanes.
__device__ __forceinline__ unsigned long long bitonic64_desc(
    unsigned long long key, int lane){
  #pragma unroll
  for (int k = 2; k <= 64; k <<= 1){
    #pragma unroll
    for (int j = k >> 1; j; j >>= 1){
      unsigned long long o = __shfl_xor(key, j, 64);
      bool keep_hi = ((lane & k) == 0) == ((lane & j) == 0);
      key = (keep_hi == (o > key)) ? o : key;
    }
  }
  return key;
}

// Full descending bitonic sort of u32 keys across 64 lanes.
__device__ __forceinline__ unsigned int bitonic32_desc(
    unsigned int key, int lane){
  #pragma unroll
  for (int k = 2; k <= 64; k <<= 1){
    #pragma unroll
    for (int j = k >> 1; j; j >>= 1){
      unsigned int o = __shfl_xor(key, j, 64);
      bool keep_hi = ((lane & k) == 0) == ((lane & j) == 0);
      key = (keep_hi == (o > key)) ? o : key;
    }
  }
  return key;
}

// ---------------- prekernel: W,b -> f64 in workspace ----------------
// cvt is exact, so downstream fma operands are identical values.
__global__ __launch_bounds__(256) void cvt_wb_v15(
    const float* __restrict__ W, const float* __restrict__ b,
    double* __restrict__ w64, double* __restrict__ b64){
  const int i = blockIdx.x * 256 + threadIdx.x;
  if (i < 8192)      w64[i] = (double)W[i];
  else if (i < 8256) b64[i - 8192] = (double)b[i - 8192];
}

// ---------------- encoder ----------------
// v15: lane = ROW (not column). Previous variants (lane=col) paid ~1 f64-pipe
// cvt per fma (broadcast x cvt'd per use): 9.4M wave-ops total. With lane=row,
// one per-lane cvt of x[r][k] serves all 64 columns: per wave (64 rows x
// 8 cols x 128 k) = 1024 fma + 128 cvt -> 4.7M wave-ops total, <=31 us under
// every f64-rate hypothesis measured so far.
//  - x tile in LDS, stride 129 dwords: bank = (r+k)%32 -> 2-way, free.
//  - W from pre-cvt'd f64 buffer via s_load (SMEM pipe); v_fma_f64 takes the
//    SGPR-pair operand directly (1-SGPR-read rule satisfied).
//  - 8 waves/block (512 thr) cover all 64 cols of 64 rows -> full-line
//    L2 write merges; x staged once per block.
// Numerics: per (r,c) chain is k=0..127 ascending, acc=fma(cvt(x),cvt(W),acc),
// init (double)b[c] -> operand-identical to v10/v11/v13 -> out BIT-IDENTICAL.
__global__ __launch_bounds__(512) void encoder_v15(
    const float* __restrict__ x, const double* __restrict__ w64,
    const double* __restrict__ b64, float* __restrict__ out){
  __shared__ float xs[64 * 129];        // 33 KB, +1-dword pad per row
  const int tid = threadIdx.x;

  { // stage 64x128 x tile, coalesced float4 loads, padded scatter
    const float4* xg4 = (const float4*)(x + ((size_t)blockIdx.x << 13));
    #pragma unroll
    for (int s = 0; s < 4; ++s){
      const int idx = tid + (s << 9);   // 0..2047 float4s
      float4 v = xg4[idx];
      const int r = idx >> 5, k4 = (idx & 31) << 2;
      float* p = &xs[r * 129 + k4];
      p[0] = v.x; p[1] = v.y; p[2] = v.z; p[3] = v.w;
    }
  }
  __syncthreads();

  const int lane = tid & 63;                                  // row
  const int wu = __builtin_amdgcn_readfirstlane(tid >> 6);    // wave (SGPR)
  const int c0 = wu << 3;                                     // 8 cols/wave
  const size_t row = ((size_t)blockIdx.x << 6) + (size_t)lane;

  double acc[8];
  const double* __restrict__ bp = b64 + c0;   // uniform -> s_load
  #pragma unroll
  for (int j = 0; j < 8; ++j) acc[j] = bp[j];

  const float* __restrict__ xrow = &xs[lane * 129];
  #pragma unroll 4
  for (int k = 0; k < 128; ++k){
    const double xk = (double)xrow[k];                 // ds_read + 1 cvt
    const double* __restrict__ wp = w64 + (k << 6) + c0;  // uniform -> s_load
    #pragma unroll
    for (int j = 0; j < 8; ++j)
      acc[j] = fma(xk, wp[j], acc[j]);
  }

  float* __restrict__ orow = out + (row << 6) + c0;
  #pragma unroll
  for (int j2 = 0; j2 < 4; ++j2){
    float2 st; st.x = (float)acc[(j2 << 1)]; st.y = (float)acc[(j2 << 1) + 1];
    *(float2*)&orow[j2 << 1] = st;
  }
}

// ---------------- edges ----------------
// Exact v11/v13 edges (proven: ~118.5 us, VGPR 28, VALUBusy ~87%).
__global__ __launch_bounds__(256, 8) void edges_v15(
    const float* __restrict__ out32, const float* __restrict__ temp,
    float* __restrict__ rows_out, float* __restrict__ cols_out){
  __shared__ double hid[4][64];         // 2 KB
  __shared__ unsigned int cl[4][128];   // 2 KB
  const int tid = threadIdx.x, wave = tid >> 6, lane = tid & 63;
  const int gb = blockIdx.x >> 8;
  const int i0 = (blockIdx.x & 255) << 2;
  const int r  = i0 + wave;
  const float* __restrict__ og = out32 + ((size_t)gb << 16);

  hid[wave][lane] = (double)og[((size_t)r << 6) + lane];

  const unsigned int base = ((unsigned int)gb << 20) | ((unsigned int)r << 10);

  // Phase 1: bits for j = m*64 + lane, with running per-lane max
  unsigned int v[16];
  unsigned int pmax = 0u;
  #pragma unroll
  for (int m = 0; m < 16; ++m){
    const unsigned int j = (unsigned int)(m << 6) + (unsigned int)lane;
    unsigned int bits = tf_bits_part(base | j);
    v[m] = (bits & ~1023u) | (1023u - j);   // low 10 bits don't feed u
    pmax = (v[m] > pmax) ? v[m] : pmax;
  }

  // Phase 2: 16th-largest lane-max (conservative surrogate for b16)
  unsigned int sorted = bitonic32_desc(pmax, lane);
  unsigned int b16p = __shfl(sorted, 15, 64);

  // conservative cut: keep j iff z_j >= z(b16') - 1.001  (score <= z + 1)
  float u16 = __uint_as_float(0x3f800000u | (b16p >> 9)) - 1.0f;
  float z16 = -__logf(-__logf(u16));
  float uc  = __expf(-__expf(-(z16 - 1.001f)));
  unsigned int cp = ((__float_as_uint(1.0f + uc) & 0x7FFFFFu) << 9) & ~1023u;

  // Phase 3: compaction of all survivors (>=16 guaranteed since cut < b16')
  int cnt = 0;
  #pragma unroll
  for (int m = 0; m < 16; ++m) cnt += (v[m] >= cp) ? 1 : 0;
  int s = cnt;
  #pragma unroll
  for (int off = 1; off < 64; off <<= 1){
    int o = __shfl_up(s, off, 64);
    s += (lane >= off) ? o : 0;
  }
  int nc = __shfl(s, 63, 64);
  nc = (nc > 128) ? 128 : nc;
  int slot = s - cnt;
  #pragma unroll
  for (int m = 0; m < 16; ++m){
    if (v[m] >= cp && slot < 128){
      cl[wave][slot] = 1023u - (v[m] & 1023u);
      ++slot;
    }
  }

  // Phase 4: exact scoring + sort
  const double Td = (double)temp[0];
  const bool act1 = (lane < nc);
  unsigned int jc1 = act1 ? cl[wave][lane] : 0u;
  unsigned long long key = score_cand(og, hid[wave], jc1, base, Td, act1);
  key = bitonic64_desc(key, lane);

  if (nc > 64){
    const int idx2 = 64 + lane;
    const bool act2 = (idx2 < nc);
    unsigned int jc2 = act2 ? cl[wave][idx2] : 0u;
    unsigned long long k2 = score_cand(og, hid[wave], jc2, base, Td, act2);
    k2 = bitonic64_desc(k2, lane);
    unsigned long long kr = __shfl(k2, 63 - lane, 64);
    key = (kr > key) ? kr : key;          // elementwise top-64 (bitonic)
    #pragma unroll
    for (int j = 32; j; j >>= 1){         // descending clean
      unsigned long long o = __shfl_xor(key, j, 64);
      bool left = (lane & j) == 0;
      bool take = left ? (o > key) : (o < key);
      key = take ? o : key;
    }
  }

  const int grow = (gb << 10) + r;
  if (lane < 16){
    rows_out[((size_t)grow << 4) + lane] = (float)grow;
    cols_out[((size_t)grow << 4) + lane] =
        (float)((gb << 10) + (1023 - (int)(key & 1023ull)));
  }
}

extern "C" void kernel_launch(void* const* d_in, const int* in_sizes, int n_in,
                              void* d_out, int out_size, void* d_ws, size_t ws_size,
                              hipStream_t stream){
  const float* x = (const float*)d_in[0];
  const float* W = (const float*)d_in[1];
  const float* b = (const float*)d_in[2];
  const float* T = (const float*)d_in[3];
  float* out      = (float*)d_out;
  float* rows_out = out + OUT_ELEMS;
  float* cols_out = rows_out + EDGE_ELEMS;

  double* w64 = (double*)d_ws;           // 8192 f64 = 64 KB
  double* b64 = w64 + 8192;              // 64 f64

  cvt_wb_v15<<<33, 256, 0, stream>>>(W, b, w64, b64);
  encoder_v15<<<512, 512, 0, stream>>>(x, w64, b64, out);
  edges_v15<<<8192, 256, 0, stream>>>(out, T, rows_out, cols_out);
}

// Round 6
// 178.108 us; speedup vs baseline: 1.2801x; 1.0622x over previous
//
#include <hip/hip_runtime.h>
#include <math.h>

// B=32 graphs, N=1024 nodes, D=128 in-dim, C=64 out-dim, K=16.
#define OUT_ELEMS 2097152   // 32768*64
#define EDGE_ELEMS 524288   // 32*1024*16

__device__ __forceinline__ unsigned int rotl32(unsigned int x, int r){
  return (x << r) | (x >> (32 - r));
}

// JAX partitionable threefry, key (0,1): counter = (0, e); out = o0 ^ o1.
__device__ __forceinline__ unsigned int tf_bits_part(unsigned int e){
  unsigned int x0 = 0u, x1 = e;
  const unsigned int ks1 = 1u;
  const unsigned int ks2 = 0x1BD11BDBu;
  x1 += ks1;
#define TFR(r) { x0 += x1; x1 = rotl32(x1, r); x1 ^= x0; }
  TFR(13) TFR(15) TFR(26) TFR(6)
  x0 += ks1; x1 += ks2 + 1u;
  TFR(17) TFR(29) TFR(16) TFR(24)
  x0 += ks2; x1 += 0u + 2u;
  TFR(13) TFR(15) TFR(26) TFR(6)
  x0 += 0u;  x1 += ks1 + 3u;
  TFR(17) TFR(29) TFR(16) TFR(24)
  x0 += ks1; x1 += ks2 + 4u;
  TFR(13) TFR(15) TFR(26) TFR(6)
  x0 += ks2; x1 += 0u + 5u;
#undef TFR
  return x0 ^ x1;
}

// hardware f64 reciprocal + 2 Newton steps: rel err ~1e-16.
__device__ __forceinline__ double rcp64(double x){
  double r;
  asm("v_rcp_f64 %0, %1" : "=v"(r) : "v"(x));
  double e = fma(-x, r, 1.0); r = fma(r, e, r);
  e = fma(-x, r, 1.0); r = fma(r, e, r);
  return r;
}

// fast e^x for x in [-740, ~1]; rel err ~2e-11 (deg-9).
__device__ __forceinline__ double fast_exp(double x){
  double fn = __builtin_rint(x * 1.4426950408889634);
  int n = (int)fn;
  double r = fma(fn, -0.6931471803691238, x);
  r = fma(fn, -1.9082149292705877e-10, r);
  double p = 2.7557319223985893e-06;
  p = fma(r, p, 2.4801587301587302e-05);
  p = fma(r, p, 1.9841269841269841e-04);
  p = fma(r, p, 1.3888888888888889e-03);
  p = fma(r, p, 8.3333333333333333e-03);
  p = fma(r, p, 4.1666666666666664e-02);
  p = fma(r, p, 1.6666666666666666e-01);
  p = fma(r, p, 0.5);
  p = fma(r, p, 1.0);
  p = fma(r, p, 1.0);
  double scale = __longlong_as_double(((long long)(n + 1023)) << 52);
  return p * scale;
}

// fast ln(x), normal positive x; atanh form; abs err ~2e-11.
__device__ __forceinline__ double fast_log(double x){
  long long bx = __double_as_longlong(x);
  long long e = (bx >> 52) - 1023;
  double m = __longlong_as_double((bx & 0xFFFFFFFFFFFFFll) |
                                  0x3FF0000000000000ll);
  int big = m > 1.4142135623730951;
  m = big ? 0.5 * m : m;
  e += big;
  double s = (m - 1.0) * rcp64(m + 1.0);
  double s2 = s * s;
  double p = fma(s2, 2.0/11.0, 2.0/9.0);
  p = fma(s2, p, 2.0/7.0);
  p = fma(s2, p, 2.0/5.0);
  p = fma(s2, p, 2.0/3.0);
  double lm = fma(s * s2, p, 2.0 * s);
  return fma((double)e, 0.6931471805599453, lm);
}

// v16 score: DISTANCE in f32 (4 parallel fma chains, fixed combine order),
// everything downstream (sigmoid, Gumbel z, key pack) exact f64 as before.
// Perturbs score by ~2.5e-8 abs vs rank-16 gaps ~0.05 -> selection flips
// expected ~0. hrowf is the wave's own h-row in LDS (f32, broadcast b128).
__device__ __forceinline__ unsigned long long score_cand32(
    const float* __restrict__ og, const float* __restrict__ hrowf,
    unsigned int jc, unsigned int base, double Td, bool act){
  const float4* cp4 = (const float4*)(og + ((size_t)jc << 6));
  const float4* hp4 = (const float4*)hrowf;
  float a0 = 0.0f, a1 = 0.0f, a2 = 0.0f, a3 = 0.0f;
  #pragma unroll 4
  for (int ch = 0; ch < 16; ++ch){
    float4 cf = cp4[ch];
    float4 hf = hp4[ch];
    float d0 = hf.x - cf.x;
    float d1 = hf.y - cf.y;
    float d2 = hf.z - cf.z;
    float d3 = hf.w - cf.w;
    a0 = fmaf(d0, d0, a0);
    a1 = fmaf(d1, d1, a1);
    a2 = fmaf(d2, d2, a2);
    a3 = fmaf(d3, d3, a3);
  }
  if (!act) return 0ull;
  double acc = (double)((a0 + a1) + (a2 + a3));
  double sgm = fast_exp(-Td * acc);
  unsigned int bits = tf_bits_part(base | jc);
  float f = __uint_as_float(0x3f800000u | (bits >> 9)) - 1.0f;
  double u = (f > 0.0f) ? (double)f : 1.1754943508222875e-38;
  double w = -fast_log(u);
  double z = -fast_log(w);
  double sc = sgm + z;
  unsigned long long kb = (unsigned long long)__double_as_longlong(sc);
  kb ^= (unsigned long long)(((long long)kb) >> 63) | 0x8000000000000000ull;
  return (kb & ~1023ull) | (unsigned long long)(1023u - jc);
}

// Full descending bitonic sort of u64 keys across 64 lanes.
__device__ __forceinline__ unsigned long long bitonic64_desc(
    unsigned long long key, int lane){
  #pragma unroll
  for (int k = 2; k <= 64; k <<= 1){
    #pragma unroll
    for (int j = k >> 1; j; j >>= 1){
      unsigned long long o = __shfl_xor(key, j, 64);
      bool keep_hi = ((lane & k) == 0) == ((lane & j) == 0);
      key = (keep_hi == (o > key)) ? o : key;
    }
  }
  return key;
}

// Full descending bitonic sort of u32 keys across 64 lanes.
__device__ __forceinline__ unsigned int bitonic32_desc(
    unsigned int key, int lane){
  #pragma unroll
  for (int k = 2; k <= 64; k <<= 1){
    #pragma unroll
    for (int j = k >> 1; j; j >>= 1){
      unsigned int o = __shfl_xor(key, j, 64);
      bool keep_hi = ((lane & k) == 0) == ((lane & j) == 0);
      key = (keep_hi == (o > key)) ? o : key;
    }
  }
  return key;
}

// ---------------- prekernel: W,b -> f64 in workspace ----------------
__global__ __launch_bounds__(256) void cvt_wb_v16(
    const float* __restrict__ W, const float* __restrict__ b,
    double* __restrict__ w64, double* __restrict__ b64){
  const int i = blockIdx.x * 256 + threadIdx.x;
  if (i < 8192)      w64[i] = (double)W[i];
  else if (i < 8256) b64[i - 8192] = (double)b[i - 8192];
}

// ---------------- encoder ----------------
// Exact v15 encoder (proven: ~38 us, out BIT-IDENTICAL, absmax 480.0).
// lane = row; W via uniform s_load from pre-cvt'd f64; x tile in padded LDS.
__global__ __launch_bounds__(512) void encoder_v16(
    const float* __restrict__ x, const double* __restrict__ w64,
    const double* __restrict__ b64, float* __restrict__ out){
  __shared__ float xs[64 * 129];        // 33 KB, +1-dword pad per row
  const int tid = threadIdx.x;

  { // stage 64x128 x tile, coalesced float4 loads, padded scatter
    const float4* xg4 = (const float4*)(x + ((size_t)blockIdx.x << 13));
    #pragma unroll
    for (int s = 0; s < 4; ++s){
      const int idx = tid + (s << 9);   // 0..2047 float4s
      float4 v = xg4[idx];
      const int r = idx >> 5, k4 = (idx & 31) << 2;
      float* p = &xs[r * 129 + k4];
      p[0] = v.x; p[1] = v.y; p[2] = v.z; p[3] = v.w;
    }
  }
  __syncthreads();

  const int lane = tid & 63;                                  // row
  const int wu = __builtin_amdgcn_readfirstlane(tid >> 6);    // wave (SGPR)
  const int c0 = wu << 3;                                     // 8 cols/wave
  const size_t row = ((size_t)blockIdx.x << 6) + (size_t)lane;

  double acc[8];
  const double* __restrict__ bp = b64 + c0;   // uniform -> s_load
  #pragma unroll
  for (int j = 0; j < 8; ++j) acc[j] = bp[j];

  const float* __restrict__ xrow = &xs[lane * 129];
  #pragma unroll 4
  for (int k = 0; k < 128; ++k){
    const double xk = (double)xrow[k];                 // ds_read + 1 cvt
    const double* __restrict__ wp = w64 + (k << 6) + c0;  // uniform -> s_load
    #pragma unroll
    for (int j = 0; j < 8; ++j)
      acc[j] = fma(xk, wp[j], acc[j]);
  }

  float* __restrict__ orow = out + (row << 6) + c0;
  #pragma unroll
  for (int j2 = 0; j2 < 4; ++j2){
    float2 st; st.x = (float)acc[(j2 << 1)]; st.y = (float)acc[(j2 << 1) + 1];
    *(float2*)&orow[j2 << 1] = st;
  }
}

// ---------------- edges ----------------
// v16: phases 1-3, sorts, and the f64 sigmoid/Gumbel/pack unchanged from the
// proven v11 kernel. Only the candidate DISTANCE moved f64 -> f32 (the
// 128 f64-op loop at ~16 cyc/op was ~2048 cyc/wave, the largest single cost
// in the problem). h-row staged as raw f32 (no cvt), read as broadcast b128.
__global__ __launch_bounds__(256, 8) void edges_v16(
    const float* __restrict__ out32, const float* __restrict__ temp,
    float* __restrict__ rows_out, float* __restrict__ cols_out){
  __shared__ float hidf[4][64];         // 1 KB
  __shared__ unsigned int cl[4][128];   // 2 KB
  const int tid = threadIdx.x, wave = tid >> 6, lane = tid & 63;
  const int gb = blockIdx.x >> 8;
  const int i0 = (blockIdx.x & 255) << 2;
  const int r  = i0 + wave;
  const float* __restrict__ og = out32 + ((size_t)gb << 16);

  hidf[wave][lane] = og[((size_t)r << 6) + lane];

  const unsigned int base = ((unsigned int)gb << 20) | ((unsigned int)r << 10);

  // Phase 1: bits for j = m*64 + lane, with running per-lane max
  unsigned int v[16];
  unsigned int pmax = 0u;
  #pragma unroll
  for (int m = 0; m < 16; ++m){
    const unsigned int j = (unsigned int)(m << 6) + (unsigned int)lane;
    unsigned int bits = tf_bits_part(base | j);
    v[m] = (bits & ~1023u) | (1023u - j);   // low 10 bits don't feed u
    pmax = (v[m] > pmax) ? v[m] : pmax;
  }

  // Phase 2: 16th-largest lane-max (conservative surrogate for b16)
  unsigned int sorted = bitonic32_desc(pmax, lane);
  unsigned int b16p = __shfl(sorted, 15, 64);

  // conservative cut: keep j iff z_j >= z(b16') - 1.001  (score <= z + 1)
  float u16 = __uint_as_float(0x3f800000u | (b16p >> 9)) - 1.0f;
  float z16 = -__logf(-__logf(u16));
  float uc  = __expf(-__expf(-(z16 - 1.001f)));
  unsigned int cp = ((__float_as_uint(1.0f + uc) & 0x7FFFFFu) << 9) & ~1023u;

  // Phase 3: compaction of all survivors (>=16 guaranteed since cut < b16')
  int cnt = 0;
  #pragma unroll
  for (int m = 0; m < 16; ++m) cnt += (v[m] >= cp) ? 1 : 0;
  int s = cnt;
  #pragma unroll
  for (int off = 1; off < 64; off <<= 1){
    int o = __shfl_up(s, off, 64);
    s += (lane >= off) ? o : 0;
  }
  int nc = __shfl(s, 63, 64);
  nc = (nc > 128) ? 128 : nc;
  int slot = s - cnt;
  #pragma unroll
  for (int m = 0; m < 16; ++m){
    if (v[m] >= cp && slot < 128){
      cl[wave][slot] = 1023u - (v[m] & 1023u);
      ++slot;
    }
  }

  // Phase 4: scoring (f32 distance, f64 tail) + sort
  const double Td = (double)temp[0];
  const bool act1 = (lane < nc);
  unsigned int jc1 = act1 ? cl[wave][lane] : 0u;
  unsigned long long key = score_cand32(og, &hidf[wave][0], jc1, base, Td, act1);
  key = bitonic64_desc(key, lane);

  if (nc > 64){
    const int idx2 = 64 + lane;
    const bool act2 = (idx2 < nc);
    unsigned int jc2 = act2 ? cl[wave][idx2] : 0u;
    unsigned long long k2 = score_cand32(og, &hidf[wave][0], jc2, base, Td, act2);
    k2 = bitonic64_desc(k2, lane);
    unsigned long long kr = __shfl(k2, 63 - lane, 64);
    key = (kr > key) ? kr : key;          // elementwise top-64 (bitonic)
    #pragma unroll
    for (int j = 32; j; j >>= 1){         // descending clean
      unsigned long long o = __shfl_xor(key, j, 64);
      bool left = (lane & j) == 0;
      bool take = left ? (o > key) : (o < key);
      key = take ? o : key;
    }
  }

  const int grow = (gb << 10) + r;
  if (lane < 16){
    rows_out[((size_t)grow << 4) + lane] = (float)grow;
    cols_out[((size_t)grow << 4) + lane] =
        (float)((gb << 10) + (1023 - (int)(key & 1023ull)));
  }
}

extern "C" void kernel_launch(void* const* d_in, const int* in_sizes, int n_in,
                              void* d_out, int out_size, void* d_ws, size_t ws_size,
                              hipStream_t stream){
  const float* x = (const float*)d_in[0];
  const float* W = (const float*)d_in[1];
  const float* b = (const float*)d_in[2];
  const float* T = (const float*)d_in[3];
  float* out      = (float*)d_out;
  float* rows_out = out + OUT_ELEMS;
  float* cols_out = rows_out + EDGE_ELEMS;

  double* w64 = (double*)d_ws;           // 8192 f64 = 64 KB
  double* b64 = w64 + 8192;              // 64 f64

  cvt_wb_v16<<<33, 256, 0, stream>>>(W, b, w64, b64);
  encoder_v16<<<512, 512, 0, stream>>>(x, w64, b64, out);
  edges_v16<<<8192, 256, 0, stream>>>(out, T, rows_out, cols_out);
}